// Round 14
// baseline (275.626 us; speedup 1.0000x reference)
//
#include <hip/hip_runtime.h>
#include <math.h>

#define NEG_SLOPE 0.2f
#define LN_EPS 1e-5f
#define NWG 256         // scatter workgroups; hist = [NB][NWG], 3-level scan

typedef __attribute__((ext_vector_type(8))) short bf16x8;
typedef __attribute__((ext_vector_type(4))) float f32x4;
typedef __attribute__((ext_vector_type(2))) float f32x2;

__device__ __forceinline__ float lrelu(float v){ return v > 0.f ? v : NEG_SLOPE * v; }
__device__ __forceinline__ float eluf (float v){ return v > 0.f ? v : expm1f(v); }

__device__ __forceinline__ unsigned short f2bf(float f){
    unsigned x = __float_as_uint(f);
    unsigned r = (x + 0x7fffu + ((x >> 16) & 1u)) >> 16;   // round-nearest-even
    return (unsigned short)r;
}

// ---------------- bucketed CSR build, atomic-free scatter (padx folded in) ----------------

__global__ __launch_bounds__(512) void k_hist(
    const int* __restrict__ dst, int* __restrict__ hist,
    const float* __restrict__ x, float4* __restrict__ x4,
    int E, int NB, int chunk, int N)
{
    __shared__ int cnt[2048];
    int t = threadIdx.x, w = blockIdx.x;
    int gid = w * 512 + t;          // NWG*512 = 131072 >= N
    if (gid < N){
        float4 r;
        r.x = x[(size_t)gid*3]; r.y = x[(size_t)gid*3+1]; r.z = x[(size_t)gid*3+2]; r.w = 0.f;
        x4[gid] = r;
    }
    for (int i = t; i < NB; i += 512) cnt[i] = 0;
    __syncthreads();
    int e0 = w * chunk, e1 = min(E, e0 + chunk);
    for (int e = e0 + t; e < e1; e += 512)
        atomicAdd(&cnt[dst[e] >> 6], 1);
    __syncthreads();
    for (int i = t; i < NB; i += 512)
        hist[(size_t)i * NWG + w] = cnt[i];
}

__global__ void k_chunk_sum(const int* __restrict__ data, int* __restrict__ partial, int M){
    __shared__ int lds[256];
    int t = threadIdx.x;
    int v = blockIdx.x * 256 + t;
    lds[t] = (v < M) ? data[v] : 0;
    __syncthreads();
    for (int s = 128; s > 0; s >>= 1){
        if (t < s) lds[t] += lds[t + s];
        __syncthreads();
    }
    if (t == 0) partial[blockIdx.x] = lds[0];
}

__global__ void k_scan_partial(int* __restrict__ partial, int n){
    __shared__ int lds[512];
    int t = threadIdx.x;
    int x = (t < n) ? partial[t] : 0;
    lds[t] = x;
    __syncthreads();
    for (int s = 1; s < 512; s <<= 1){
        int a = (t >= s) ? lds[t - s] : 0;
        __syncthreads();
        lds[t] += a;
        __syncthreads();
    }
    if (t < n) partial[t] = lds[t] - x;   // exclusive
}

__global__ void k_scan_apply(int* __restrict__ data, const int* __restrict__ partial, int M){
    __shared__ int lds[256];
    int t = threadIdx.x;
    int v = blockIdx.x * 256 + t;
    int x = (v < M) ? data[v] : 0;
    lds[t] = x;
    __syncthreads();
    for (int s = 1; s < 256; s <<= 1){
        int a = (t >= s) ? lds[t - s] : 0;
        __syncthreads();
        lds[t] += a;
        __syncthreads();
    }
    if (v < M) data[v] = partial[blockIdx.x] + lds[t] - x;   // exclusive
}

__global__ __launch_bounds__(512) void k_pscatter(
    const int* __restrict__ src, const int* __restrict__ dst,
    const int* __restrict__ shist, unsigned* __restrict__ ebuf, int E, int NB, int chunk)
{
    __shared__ int cur[2048];
    int t = threadIdx.x, w = blockIdx.x;
    for (int i = t; i < NB; i += 512) cur[i] = shist[(size_t)i * NWG + w];
    __syncthreads();
    int e0 = w * chunk, e1 = min(E, e0 + chunk);
    for (int e = e0 + t; e < e1; e += 512){
        int d = dst[e];
        int pos = atomicAdd(&cur[d >> 6], 1);
        ebuf[pos] = ((unsigned)(d & 63) << 26) | (unsigned)src[e];
    }
}

// one wave per bucket: local degree count -> wave-scan -> row_ptr + LDS-cursor fill
__global__ __launch_bounds__(256) void k_bfill(
    const unsigned* __restrict__ ebuf, const int* __restrict__ shist,
    int* __restrict__ row_ptr, int* __restrict__ col, int* __restrict__ dcol,
    int N, int NB, int E)
{
    __shared__ int scnt[4][64];
    int t = threadIdx.x, lane = t & 63, w = t >> 6;
    int b = blockIdx.x * 4 + w;
    bool act = b < NB;
    if (t == 0 && blockIdx.x == 0) row_ptr[N] = E;
    scnt[w][lane] = 0;
    __syncthreads();
    int ebeg = 0, eend = 0;
    if (act){
        ebeg = shist[(size_t)b * NWG];
        eend = (b + 1 < NB) ? shist[(size_t)(b + 1) * NWG] : E;
    }
    for (int j = ebeg + lane; j < eend; j += 64)
        atomicAdd(&scnt[w][ebuf[j] >> 26], 1);
    __syncthreads();
    int deg = scnt[w][lane];
    int incl = deg;
    #pragma unroll
    for (int k = 1; k < 64; k <<= 1){
        int up = __shfl_up(incl, k);
        if (lane >= k) incl += up;
    }
    int excl = incl - deg;
    int base = act ? ebeg : 0;
    int v = b * 64 + lane;
    if (act && v < N) row_ptr[v] = base + excl;
    __syncthreads();
    scnt[w][lane] = base + excl;
    __syncthreads();
    for (int j = ebeg + lane; j < eend; j += 64){
        unsigned u = ebuf[j];
        int pos = atomicAdd(&scnt[w][u >> 26], 1);
        col[pos]  = (int)(u & 0x03FFFFFFu);
        dcol[pos] = b * 64 + (int)(u >> 26);
    }
}

// ---------------- layer 1: fused logits + attn + agg + bias + ELU + LN -> bf16 ----------------
// es[s] = x[s]·(W1 a_src) per head; ed[v] = x[v]·(W1 a_dst). No lin1 pass, no es array.
// sum_e p_e*(x[s]@W) = (sum_e p_e*x[s])@W ; lane = (head hsel=lane>>4, sub=lane&15)

__global__ __launch_bounds__(256) void k_agg1(
    const float4* __restrict__ x4, const float* __restrict__ W1,
    const float* __restrict__ as1, const float* __restrict__ ad1,
    const int* __restrict__ row_ptr, const int* __restrict__ col,
    const float* __restrict__ b1, const float* __restrict__ g1, const float* __restrict__ be1,
    unsigned* __restrict__ h1b, int N)
{
    __shared__ float sAW[24];   // [0..11]=asW[h*3+d], [12..23]=adW[h*3+d]
    int t = threadIdx.x, lane = t & 63, w = t >> 6;
    if (t < 24){
        int id = t % 12, h = id / 3, d = id % 3;
        const float* a = (t < 12) ? as1 : ad1;
        float s = 0.f;
        #pragma unroll 8
        for (int c = 0; c < 32; ++c) s += W1[d*128 + h*32 + c] * a[h*32 + c];
        sAW[t] = s;
    }
    __syncthreads();
    int v = blockIdx.x * 4 + w;
    if (v >= N) return;
    int hsel = lane >> 4, sub = lane & 15;
    float as0 = sAW[hsel*3], asv1 = sAW[hsel*3+1], as2 = sAW[hsel*3+2];
    float ad0 = sAW[12+hsel*3], adv1 = sAW[12+hsel*3+1], ad2 = sAW[12+hsel*3+2];
    float4 xv = x4[v];
    float edh = xv.x*ad0 + xv.y*adv1 + xv.z*ad2;
    float sa0 = 0.f, sa1 = 0.f, sa2 = 0.f, sp_ = 0.f;
    int beg = row_ptr[v], end = row_ptr[v+1];
    int j = beg + sub;
    for (; j + 16 < end; j += 32){
        int sA = col[j], sB = col[j + 16];
        float4 a = x4[sA];
        float4 b = x4[sB];
        float qA = a.x*as0 + a.y*asv1 + a.z*as2;
        float qB = b.x*as0 + b.y*asv1 + b.z*as2;
        float pA = __expf(lrelu(qA + edh));
        float pB = __expf(lrelu(qB + edh));
        sp_ += pA + pB;
        sa0 += pA*a.x + pB*b.x;
        sa1 += pA*a.y + pB*b.y;
        sa2 += pA*a.z + pB*b.z;
    }
    if (j < end){
        int s = col[j];
        float4 a = x4[s];
        float q = a.x*as0 + a.y*asv1 + a.z*as2;
        float p = __expf(lrelu(q + edh));
        sp_ += p;
        sa0 += p*a.x; sa1 += p*a.y; sa2 += p*a.z;
    }
    if (sub == 0){   // self loop, once per head
        float qs = xv.x*as0 + xv.y*asv1 + xv.z*as2;
        float p = __expf(lrelu(qs + edh));
        sp_ += p;
        sa0 += p*xv.x; sa1 += p*xv.y; sa2 += p*xv.z;
    }
    #pragma unroll
    for (int k = 1; k < 16; k <<= 1){
        sa0 += __shfl_xor(sa0, k); sa1 += __shfl_xor(sa1, k);
        sa2 += __shfl_xor(sa2, k); sp_ += __shfl_xor(sp_, k);
    }
    float inv = 1.f / (sp_ + 1e-16f);
    float A0 = sa0*inv, A1 = sa1*inv, A2 = sa2*inv;
    int c = lane * 2;   // channels c,c+1 ; head (c>>5) == hsel
    float h0 = A0*W1[c  ] + A1*W1[128+c  ] + A2*W1[256+c  ];
    float h1v= A0*W1[c+1] + A1*W1[128+c+1] + A2*W1[256+c+1];
    float2 bb = *(const float2*)(b1 + c);
    float oA = eluf(h0 + bb.x);
    float oB = eluf(h1v + bb.y);
    float su = oA + oB;
    #pragma unroll
    for (int k = 32; k >= 1; k >>= 1) su += __shfl_xor(su, k);
    float mean = su * (1.f/128.f);
    float aA = oA - mean, aB = oB - mean;
    float vs = aA*aA + aB*aB;
    #pragma unroll
    for (int k = 32; k >= 1; k >>= 1) vs += __shfl_xor(vs, k);
    float rstd = rsqrtf(vs * (1.f/128.f) + LN_EPS);
    float2 gg = *(const float2*)(g1 + c);
    float2 ee = *(const float2*)(be1 + c);
    float rx = aA*rstd*gg.x + ee.x, ry = aB*rstd*gg.y + ee.y;
    h1b[(size_t)v*64 + lane] = (unsigned)f2bf(rx) | ((unsigned)f2bf(ry) << 16);
}

// ---------------- layer 2 linear via MFMA: h1b[N,128]bf16 @ W2[128,64] -> fp8 ----------------

__global__ __launch_bounds__(256) void k_lin2(
    const unsigned short* __restrict__ h1b,   // [N][128] bf16
    const float* __restrict__ W2,             // [128][64] fp32
    const float* __restrict__ asrc, const float* __restrict__ adst,
    unsigned char* __restrict__ h2b8, float* __restrict__ es2, float* __restrict__ ed2, int N)
{
    int t = threadIdx.x, lane = t & 63, w = t >> 6;
    int vb = blockIdx.x * 64 + w * 16;
    if (vb >= N) return;
    int lo4 = lane & 15, hi4 = lane >> 4;

    int arow = vb + lo4; if (arow >= N) arow = N - 1;
    const unsigned short* ap = h1b + (size_t)arow*128 + hi4*8;
    bf16x8 a0 = *(const bf16x8*)(ap);
    bf16x8 a1 = *(const bf16x8*)(ap + 32);
    bf16x8 a2 = *(const bf16x8*)(ap + 64);
    bf16x8 a3 = *(const bf16x8*)(ap + 96);

    f32x4 acc[4];
    #pragma unroll
    for (int nt = 0; nt < 4; ++nt) acc[nt] = (f32x4){0.f, 0.f, 0.f, 0.f};

    #pragma unroll
    for (int nt = 0; nt < 4; ++nt){
        int cb = nt*16 + lo4;
        #pragma unroll
        for (int kt = 0; kt < 4; ++kt){
            const float* wp = W2 + (size_t)(kt*32 + hi4*8)*64 + cb;
            bf16x8 b;
            #pragma unroll
            for (int j = 0; j < 8; ++j) b[j] = (short)f2bf(wp[(size_t)j*64]);
            bf16x8 a = (kt==0) ? a0 : (kt==1) ? a1 : (kt==2) ? a2 : a3;
            acc[nt] = __builtin_amdgcn_mfma_f32_16x16x32_bf16(a, b, acc[nt], 0, 0, 0);
        }
    }

    float sa0 = asrc[lo4], sa1 = asrc[16+lo4], sa2 = asrc[32+lo4], sa3 = asrc[48+lo4];
    float sb0 = adst[lo4], sb1 = adst[16+lo4], sb2 = adst[32+lo4], sb3 = adst[48+lo4];

    #pragma unroll
    for (int reg = 0; reg < 4; ++reg){
        int nr = vb + hi4*4 + reg;
        bool ok = nr < N;
        float c0 = acc[0][reg], c1 = acc[1][reg], c2 = acc[2][reg], c3 = acc[3][reg];
        if (ok){
            int wv = __builtin_amdgcn_cvt_pk_fp8_f32(c0, c1, 0, false);
            wv = __builtin_amdgcn_cvt_pk_fp8_f32(c2, c3, wv, true);
            unsigned char* hp = h2b8 + (size_t)nr*64 + lo4;
            hp[ 0] = (unsigned char)( wv        & 255);
            hp[16] = (unsigned char)((wv >>  8) & 255);
            hp[32] = (unsigned char)((wv >> 16) & 255);
            hp[48] = (unsigned char)((wv >> 24) & 255);
        }
        float ps0 = c0*sa0 + c1*sa1, ps1 = c2*sa2 + c3*sa3;
        float pd0 = c0*sb0 + c1*sb1, pd1 = c2*sb2 + c3*sb3;
        #pragma unroll
        for (int m = 8; m >= 1; m >>= 1){
            ps0 += __shfl_xor(ps0, m); ps1 += __shfl_xor(ps1, m);
            pd0 += __shfl_xor(pd0, m); pd1 += __shfl_xor(pd1, m);
        }
        if (ok && lo4 == 0){
            float2 e; e.x = ps0; e.y = ps1;
            float2 d; d.x = pd0; d.y = pd1;
            *(float2*)(es2 + (size_t)nr*2) = e;
            *(float2*)(ed2 + (size_t)nr*2) = d;
        }
    }
}

// ---------------- edge-parallel attention weights: p2[e] = exp(lrelu(es[src]+ed[dst])) ----------------

__global__ void k_prep2(const int* __restrict__ col, const int* __restrict__ dcol,
                        const float* __restrict__ es2, const float* __restrict__ ed2,
                        float2* __restrict__ p2, int E)
{
    int e = blockIdx.x * 256 + threadIdx.x;
    if (e < E){
        int s = col[e], d = dcol[e];
        float2 es = *(const float2*)(es2 + (size_t)s*2);
        float2 ed = *(const float2*)(ed2 + (size_t)d*2);
        float2 r;
        r.x = __expf(lrelu(es.x + ed.x));
        r.y = __expf(lrelu(es.y + ed.y));
        p2[e] = r;
    }
}

// ---------------- layer 2: fused attn+agg, EPG=4, fp8 rows, precomputed p2 ----------------
// lane = (slot g = lane>>4, l = lane&15); lane covers channels 4l..4l+3 (head l>>3).
// No LDS, no prepass: inner chain is col -> h2b gather only.

__global__ __launch_bounds__(256) void k_agg2(
    const unsigned* __restrict__ h2b,          // [N][16] u32 = fp8[N][64]
    const float* __restrict__ es2, const float* __restrict__ ed2,
    const float2* __restrict__ p2,
    const int* __restrict__ row_ptr, const int* __restrict__ col,
    const float4* __restrict__ x4, const float* __restrict__ Wskip, const float* __restrict__ bskip,
    const float* __restrict__ b2, const float* __restrict__ g2, const float* __restrict__ be2,
    float* __restrict__ h2, int N)
{
    int t = threadIdx.x, lane = t & 63, w = t >> 6;
    int v = blockIdx.x * 4 + w;
    if (v >= N) return;
    int g = lane >> 4, l = lane & 15;
    int hsel = l >> 3;
    float2 edv = *(const float2*)(ed2 + (size_t)v*2);
    float2 esv = *(const float2*)(es2 + (size_t)v*2);
    float eh = (hsel ? esv.y : esv.x) + (hsel ? edv.y : edv.x);
    float pself = (g == 0) ? __expf(lrelu(eh)) : 0.f;
    unsigned us = h2b[(size_t)v*16 + l];
    f32x2 acc01, acc23;
    {
        f32x2 slo = __builtin_amdgcn_cvt_pk_f32_fp8((int)us, false);
        f32x2 shi = __builtin_amdgcn_cvt_pk_f32_fp8((int)us, true);
        f32x2 ps = {pself, pself};
        acc01 = ps * slo;
        acc23 = ps * shi;
    }
    float sum_p = pself;

    int beg = row_ptr[v], end = row_ptr[v+1];
    for (int i0 = beg; i0 < end; i0 += 16){
        int j0 = i0 + g, j1 = j0 + 4, j2 = j0 + 8, j3 = j0 + 12;
        bool v0 = j0 < end, v1 = j1 < end, v2 = j2 < end, v3 = j3 < end;
        int jj0 = v0 ? j0 : beg, jj1 = v1 ? j1 : beg;
        int jj2 = v2 ? j2 : beg, jj3 = v3 ? j3 : beg;
        // broadcast loads (16 lanes same address), all independent
        int s0 = col[jj0], s1 = col[jj1], s2 = col[jj2], s3 = col[jj3];
        float2 q0 = p2[jj0], q1 = p2[jj1], q2 = p2[jj2], q3 = p2[jj3];
        unsigned u0 = h2b[(size_t)s0*16 + l];
        unsigned u1 = h2b[(size_t)s1*16 + l];
        unsigned u2 = h2b[(size_t)s2*16 + l];
        unsigned u3 = h2b[(size_t)s3*16 + l];
        float p0 = v0 ? (hsel ? q0.y : q0.x) : 0.f;
        float p1 = v1 ? (hsel ? q1.y : q1.x) : 0.f;
        float p2v = v2 ? (hsel ? q2.y : q2.x) : 0.f;
        float p3 = v3 ? (hsel ? q3.y : q3.x) : 0.f;
        sum_p += (p0 + p1) + (p2v + p3);
        f32x2 p0v = {p0, p0}, p1v = {p1, p1}, p2vv = {p2v, p2v}, p3v = {p3, p3};
        acc01 += p0v * __builtin_amdgcn_cvt_pk_f32_fp8((int)u0, false)
               + p1v * __builtin_amdgcn_cvt_pk_f32_fp8((int)u1, false)
               + p2vv * __builtin_amdgcn_cvt_pk_f32_fp8((int)u2, false)
               + p3v * __builtin_amdgcn_cvt_pk_f32_fp8((int)u3, false);
        acc23 += p0v * __builtin_amdgcn_cvt_pk_f32_fp8((int)u0, true)
               + p1v * __builtin_amdgcn_cvt_pk_f32_fp8((int)u1, true)
               + p2vv * __builtin_amdgcn_cvt_pk_f32_fp8((int)u2, true)
               + p3v * __builtin_amdgcn_cvt_pk_f32_fp8((int)u3, true);
    }
    float acc[4] = {acc01.x, acc01.y, acc23.x, acc23.y};
    #pragma unroll
    for (int j = 0; j < 4; ++j){
        acc[j] += __shfl_xor(acc[j], 16);
        acc[j] += __shfl_xor(acc[j], 32);
    }
    sum_p += __shfl_xor(sum_p, 16);
    sum_p += __shfl_xor(sum_p, 32);
    float inv = 1.f / (sum_p + 1e-16f);
    #pragma unroll
    for (int j = 0; j < 4; ++j) acc[j] *= inv;
    // head mean: lane l pairs with l^8 (channels c and c+32)
    float4 xv = x4[v];
    float xa = xv.x, xb = xv.y, xc = xv.z;
    int cc = (l & 7) * 4;
    float z[4];
    #pragma unroll
    for (int j = 0; j < 4; ++j){
        float other = __shfl_xor(acc[j], 8);
        float o = eluf(0.5f*(acc[j] + other) + b2[cc+j]);
        float sk = xa*Wskip[cc+j] + xb*Wskip[32+cc+j] + xc*Wskip[64+cc+j] + bskip[cc+j];
        z[j] = o + sk;
    }
    float su = z[0]+z[1]+z[2]+z[3];
    su += __shfl_xor(su,1); su += __shfl_xor(su,2); su += __shfl_xor(su,4);
    float mean = su * (1.f/32.f);
    float vs = 0.f;
    #pragma unroll
    for (int j = 0; j < 4; ++j){ float d = z[j]-mean; vs += d*d; }
    vs += __shfl_xor(vs,1); vs += __shfl_xor(vs,2); vs += __shfl_xor(vs,4);
    float rstd = rsqrtf(vs * (1.f/32.f) + LN_EPS);
    if (g == 0 && l < 8){
        float4 r;
        r.x = (z[0]-mean)*rstd*g2[cc  ] + be2[cc  ];
        r.y = (z[1]-mean)*rstd*g2[cc+1] + be2[cc+1];
        r.z = (z[2]-mean)*rstd*g2[cc+2] + be2[cc+2];
        r.w = (z[3]-mean)*rstd*g2[cc+3] + be2[cc+3];
        *(float4*)(h2 + (size_t)v*32 + cc) = r;
    }
}

// ---------------- pooling: per-graph mean/max/std (batch sorted) + projection ----------------

__global__ __launch_bounds__(256) void k_pool(
    const float* __restrict__ h2, const int* __restrict__ batch,
    const float* __restrict__ Wp, const float* __restrict__ bp,
    float* __restrict__ out, int N)
{
    int g = blockIdx.x; int t = threadIdx.x;
    __shared__ int sBeg, sEnd;
    if (t == 0){
        int lo = 0, hi = N;
        while (lo < hi){ int mid = (lo+hi) >> 1; if (batch[mid] < g) lo = mid+1; else hi = mid; }
        sBeg = lo;
        lo = sBeg; hi = N;
        while (lo < hi){ int mid = (lo+hi) >> 1; if (batch[mid] < g+1) lo = mid+1; else hi = mid; }
        sEnd = lo;
    }
    __syncthreads();
    int beg = sBeg, end = sEnd;
    int ch = t & 31, grp = t >> 5;
    float sum = 0.f, sq = 0.f, mx = -INFINITY;
    for (int i = beg + grp; i < end; i += 8){
        float val = h2[(size_t)i*32 + ch];
        sum += val; sq += val*val; mx = fmaxf(mx, val);
    }
    __shared__ float lsum[256], lsq[256], lmx[256];
    lsum[t] = sum; lsq[t] = sq; lmx[t] = mx;
    __syncthreads();
    for (int s = 4; s >= 1; s >>= 1){
        if (grp < s){
            lsum[t] += lsum[t + s*32];
            lsq [t] += lsq [t + s*32];
            lmx [t]  = fmaxf(lmx[t], lmx[t + s*32]);
        }
        __syncthreads();
    }
    __shared__ float feat[96];
    if (t < 32){
        float cnt = fmaxf((float)(end - beg), 1.f);
        float mean = lsum[t] / cnt;
        float var  = lsq[t] / cnt - mean*mean;
        feat[t]      = mean;
        feat[32 + t] = lmx[t];
        feat[64 + t] = sqrtf(fmaxf(var, 0.f));
    }
    __syncthreads();
    if (t < 48){
        float acc = bp[t];
        #pragma unroll 8
        for (int k = 0; k < 96; ++k) acc += feat[k] * Wp[k*48 + t];
        out[(size_t)g*48 + t] = acc;
    }
}

// ---------------- launcher ----------------

extern "C" void kernel_launch(void* const* d_in, const int* in_sizes, int n_in,
                              void* d_out, int out_size, void* d_ws, size_t ws_size,
                              hipStream_t stream)
{
    const float* x     = (const float*)d_in[0];
    const int*   ei    = (const int*)  d_in[1];
    const int*   batch = (const int*)  d_in[2];
    const float* W1    = (const float*)d_in[3];
    const float* as1   = (const float*)d_in[4];
    const float* ad1   = (const float*)d_in[5];
    const float* b1    = (const float*)d_in[6];
    const float* W2    = (const float*)d_in[7];
    const float* as2   = (const float*)d_in[8];
    const float* ad2   = (const float*)d_in[9];
    const float* b2    = (const float*)d_in[10];
    const float* Wskip = (const float*)d_in[11];
    const float* bskip = (const float*)d_in[12];
    const float* g1    = (const float*)d_in[13];
    const float* be1   = (const float*)d_in[14];
    const float* g2    = (const float*)d_in[15];
    const float* be2   = (const float*)d_in[16];
    const float* Wp    = (const float*)d_in[17];
    const float* bp    = (const float*)d_in[18];

    int N = in_sizes[0] / 3;
    int E = in_sizes[1] / 2;
    int B = out_size / 48;
    const int* src = ei;
    const int* dst = ei + E;
    int NBUK = (N + 63) / 64;              // 1563
    int chunk = (E + NWG - 1) / NWG;
    int M = NBUK * NWG;                    // 400128

    char* w = (char*)d_ws;
    auto alloc = [&](size_t bytes) -> char* {
        char* p = w; w += (bytes + 255) & ~(size_t)255; return p;
    };
    int*   row_ptr = (int*)  alloc((size_t)(N+1)*4);
    int*   hist    = (int*)  alloc((size_t)M*4);
    int*   p1      = (int*)  alloc(8*1024);            // level-1 partials (<=2048)
    int*   p2s     = (int*)  alloc(4*1024);            // level-2 partials (<=512)
    int*   col     = (int*)  alloc((size_t)E*4);
    int*   dcol    = (int*)  alloc((size_t)E*4);
    float2* p2     = (float2*)alloc((size_t)E*8);
    unsigned* h2b  = (unsigned*)alloc((size_t)N*64);   // fp8[N][64]
    float* es      = (float*)alloc((size_t)N*2*4);     // layer2 es2
    float* ed      = (float*)alloc((size_t)N*2*4);     // layer2 ed2
    unsigned* h1b  = (unsigned*)alloc((size_t)N*64*4); // bf16[N][128]
    float* h2      = (float*)alloc((size_t)N*32*4);
    float4* x4     = (float4*)alloc((size_t)N*16);
    unsigned* ebuf = (unsigned*)h2;                    // alias: ebuf dead before agg2 writes h2
    (void)ws_size;

    int mb  = (M + 255) / 256;             // 1563
    int mb2 = (mb + 255) / 256;            // 7
    int nb  = (N + 3) / 4;
    int nb2 = (N + 63) / 64;
    int eb  = (E + 255) / 256;

    k_hist        <<<NWG, 512, 0, stream>>>(dst, hist, x, x4, E, NBUK, chunk, N);
    k_chunk_sum   <<<mb, 256, 0, stream>>>(hist, p1, M);
    k_chunk_sum   <<<mb2, 256, 0, stream>>>(p1, p2s, mb);
    k_scan_partial<<<1, 512, 0, stream>>>(p2s, mb2);
    k_scan_apply  <<<mb2, 256, 0, stream>>>(p1, p2s, mb);
    k_scan_apply  <<<mb, 256, 0, stream>>>(hist, p1, M);
    k_pscatter    <<<NWG, 512, 0, stream>>>(src, dst, hist, ebuf, E, NBUK, chunk);
    k_bfill       <<<(NBUK + 3) / 4, 256, 0, stream>>>(ebuf, hist, row_ptr, col, dcol, N, NBUK, E);

    k_agg1 <<<nb, 256, 0, stream>>>(x4, W1, as1, ad1, row_ptr, col, b1, g1, be1, h1b, N);
    k_lin2 <<<nb2, 256, 0, stream>>>((const unsigned short*)h1b, W2, as2, ad2,
                                     (unsigned char*)h2b, es, ed, N);
    k_prep2<<<eb, 256, 0, stream>>>(col, dcol, es, ed, p2, E);
    k_agg2 <<<nb, 256, 0, stream>>>(h2b, es, ed, p2, row_ptr, col,
                                    x4, Wskip, bskip, b2, g2, be2, h2, N);
    k_pool <<<B, 256, 0, stream>>>(h2, batch, Wp, bp, (float*)d_out, N);
}

// Round 15
// 196.990 us; speedup vs baseline: 1.3992x; 1.3992x over previous
//
#include <hip/hip_runtime.h>
#include <math.h>

#define NEG_SLOPE 0.2f
#define LN_EPS 1e-5f
#define NWG 256         // scatter workgroups; hist = [NB][NWG]

typedef __attribute__((ext_vector_type(8))) short bf16x8;
typedef __attribute__((ext_vector_type(4))) float f32x4;
typedef __attribute__((ext_vector_type(2))) float f32x2;

__device__ __forceinline__ float lrelu(float v){ return v > 0.f ? v : NEG_SLOPE * v; }
__device__ __forceinline__ float eluf (float v){ return v > 0.f ? v : expm1f(v); }

__device__ __forceinline__ unsigned short f2bf(float f){
    unsigned x = __float_as_uint(f);
    unsigned r = (x + 0x7fffu + ((x >> 16) & 1u)) >> 16;   // round-nearest-even
    return (unsigned short)r;
}

// ---------------- bucketed CSR build, atomic-free scatter (padx folded in) ----------------

__global__ __launch_bounds__(512) void k_hist(
    const int* __restrict__ dst, int* __restrict__ hist,
    const float* __restrict__ x, float4* __restrict__ x4,
    int E, int NB, int chunk, int N)
{
    __shared__ int cnt[2048];
    int t = threadIdx.x, w = blockIdx.x;
    int gid = w * 512 + t;          // NWG*512 = 131072 >= N
    if (gid < N){
        float4 r;
        r.x = x[(size_t)gid*3]; r.y = x[(size_t)gid*3+1]; r.z = x[(size_t)gid*3+2]; r.w = 0.f;
        x4[gid] = r;
    }
    for (int i = t; i < NB; i += 512) cnt[i] = 0;
    __syncthreads();
    int e0 = w * chunk, e1 = min(E, e0 + chunk);
    for (int e = e0 + t; e < e1; e += 512)
        atomicAdd(&cnt[dst[e] >> 6], 1);
    __syncthreads();
    for (int i = t; i < NB; i += 512)
        hist[(size_t)i * NWG + w] = cnt[i];
}

__global__ void k_chunk_sum(const int* __restrict__ data, int* __restrict__ partial, int M){
    __shared__ int lds[256];
    int t = threadIdx.x;
    int v = blockIdx.x * 256 + t;
    lds[t] = (v < M) ? data[v] : 0;
    __syncthreads();
    for (int s = 128; s > 0; s >>= 1){
        if (t < s) lds[t] += lds[t + s];
        __syncthreads();
    }
    if (t == 0) partial[blockIdx.x] = lds[0];
}

// single block, 1024 threads: in-place exclusive scan of p[0..n), n <= 2048
__global__ __launch_bounds__(1024) void k_scan_mid(int* __restrict__ p, int n){
    __shared__ int lds[1024];
    int t = threadIdx.x;
    int i0 = 2*t, i1 = 2*t + 1;
    int a = (i0 < n) ? p[i0] : 0;
    int b = (i1 < n) ? p[i1] : 0;
    int pair = a + b;
    lds[t] = pair;
    __syncthreads();
    for (int s = 1; s < 1024; s <<= 1){
        int add = (t >= s) ? lds[t - s] : 0;
        __syncthreads();
        lds[t] += add;
        __syncthreads();
    }
    int excl = lds[t] - pair;
    if (i0 < n) p[i0] = excl;
    if (i1 < n) p[i1] = excl + a;
}

__global__ void k_scan_apply(int* __restrict__ data, const int* __restrict__ partial, int M){
    __shared__ int lds[256];
    int t = threadIdx.x;
    int v = blockIdx.x * 256 + t;
    int x = (v < M) ? data[v] : 0;
    lds[t] = x;
    __syncthreads();
    for (int s = 1; s < 256; s <<= 1){
        int a = (t >= s) ? lds[t - s] : 0;
        __syncthreads();
        lds[t] += a;
        __syncthreads();
    }
    if (v < M) data[v] = partial[blockIdx.x] + lds[t] - x;   // exclusive
}

__global__ __launch_bounds__(512) void k_pscatter(
    const int* __restrict__ src, const int* __restrict__ dst,
    const int* __restrict__ shist, unsigned* __restrict__ ebuf, int E, int NB, int chunk)
{
    __shared__ int cur[2048];
    int t = threadIdx.x, w = blockIdx.x;
    for (int i = t; i < NB; i += 512) cur[i] = shist[(size_t)i * NWG + w];
    __syncthreads();
    int e0 = w * chunk, e1 = min(E, e0 + chunk);
    for (int e = e0 + t; e < e1; e += 512){
        int d = dst[e];
        int pos = atomicAdd(&cur[d >> 6], 1);
        ebuf[pos] = ((unsigned)(d & 63) << 26) | (unsigned)src[e];
    }
}

// one wave per bucket: local degree count -> wave-scan -> row_ptr + LDS-cursor fill
__global__ __launch_bounds__(256) void k_bfill(
    const unsigned* __restrict__ ebuf, const int* __restrict__ shist,
    int* __restrict__ row_ptr, int* __restrict__ col, int N, int NB, int E)
{
    __shared__ int scnt[4][64];
    int t = threadIdx.x, lane = t & 63, w = t >> 6;
    int b = blockIdx.x * 4 + w;
    bool act = b < NB;
    if (t == 0 && blockIdx.x == 0) row_ptr[N] = E;
    scnt[w][lane] = 0;
    __syncthreads();
    int ebeg = 0, eend = 0;
    if (act){
        ebeg = shist[(size_t)b * NWG];
        eend = (b + 1 < NB) ? shist[(size_t)(b + 1) * NWG] : E;
    }
    for (int j = ebeg + lane; j < eend; j += 64)
        atomicAdd(&scnt[w][ebuf[j] >> 26], 1);
    __syncthreads();
    int deg = scnt[w][lane];
    int incl = deg;
    #pragma unroll
    for (int k = 1; k < 64; k <<= 1){
        int up = __shfl_up(incl, k);
        if (lane >= k) incl += up;
    }
    int excl = incl - deg;
    int base = act ? ebeg : 0;
    int v = b * 64 + lane;
    if (act && v < N) row_ptr[v] = base + excl;
    __syncthreads();
    scnt[w][lane] = base + excl;
    __syncthreads();
    for (int j = ebeg + lane; j < eend; j += 64){
        unsigned u = ebuf[j];
        int pos = atomicAdd(&scnt[w][u >> 26], 1);
        col[pos] = (int)(u & 0x03FFFFFFu);
    }
}

// ---------------- layer 1: fused logits + attn + agg + bias + ELU + LN -> bf16 ----------------
// 2 nodes per wave (independent gather chains). lane = (head hsel=lane>>4, sub=lane&15).

__global__ __launch_bounds__(256) void k_agg1(
    const float4* __restrict__ x4, const float* __restrict__ W1,
    const float* __restrict__ as1, const float* __restrict__ ad1,
    const int* __restrict__ row_ptr, const int* __restrict__ col,
    const float* __restrict__ b1, const float* __restrict__ g1, const float* __restrict__ be1,
    unsigned* __restrict__ h1b, int N)
{
    __shared__ float sAW[24];   // [0..11]=asW[h*3+d], [12..23]=adW[h*3+d]
    int t = threadIdx.x, lane = t & 63, w = t >> 6;
    if (t < 24){
        int id = t % 12, h = id / 3, d = id % 3;
        const float* a = (t < 12) ? as1 : ad1;
        float s = 0.f;
        #pragma unroll 8
        for (int c = 0; c < 32; ++c) s += W1[d*128 + h*32 + c] * a[h*32 + c];
        sAW[t] = s;
    }
    __syncthreads();
    int va = blockIdx.x * 8 + w * 2;
    if (va >= N) return;
    int vb = va + 1;
    bool vbOK = vb < N;
    int vbL = vbOK ? vb : va;
    int hsel = lane >> 4, sub = lane & 15;
    float as0 = sAW[hsel*3], asv1 = sAW[hsel*3+1], as2 = sAW[hsel*3+2];
    float ad0 = sAW[12+hsel*3], adv1 = sAW[12+hsel*3+1], ad2 = sAW[12+hsel*3+2];
    float4 xvA = x4[va];
    float4 xvB = x4[vbL];
    float edhA = xvA.x*ad0 + xvA.y*adv1 + xvA.z*ad2;
    float edhB = xvB.x*ad0 + xvB.y*adv1 + xvB.z*ad2;
    int begA = row_ptr[va], endA = row_ptr[va+1];
    int begB = 0, endB = 0;
    if (vbOK){ begB = row_ptr[vb]; endB = row_ptr[vb+1]; }
    float sA0=0.f, sA1=0.f, sA2=0.f, spA=0.f;
    float sB0=0.f, sB1=0.f, sB2=0.f, spB=0.f;
    int jA = begA + sub, jB = begB + sub;
    while (jA < endA || jB < endB){
        bool aA = jA < endA, aB = jB < endB;
        int sa_ = aA ? col[jA] : va;
        int sb_ = aB ? col[jB] : va;
        float4 a = x4[sa_];
        float4 b = x4[sb_];
        float qA = a.x*as0 + a.y*asv1 + a.z*as2;
        float qB = b.x*as0 + b.y*asv1 + b.z*as2;
        float pA = aA ? __expf(lrelu(qA + edhA)) : 0.f;
        float pB = aB ? __expf(lrelu(qB + edhB)) : 0.f;
        spA += pA; sA0 += pA*a.x; sA1 += pA*a.y; sA2 += pA*a.z;
        spB += pB; sB0 += pB*b.x; sB1 += pB*b.y; sB2 += pB*b.z;
        jA += 16; jB += 16;
    }
    if (sub == 0){   // self loops, once per head
        float qs = xvA.x*as0 + xvA.y*asv1 + xvA.z*as2;
        float p = __expf(lrelu(qs + edhA));
        spA += p; sA0 += p*xvA.x; sA1 += p*xvA.y; sA2 += p*xvA.z;
        if (vbOK){
            float qt = xvB.x*as0 + xvB.y*asv1 + xvB.z*as2;
            float q2 = __expf(lrelu(qt + edhB));
            spB += q2; sB0 += q2*xvB.x; sB1 += q2*xvB.y; sB2 += q2*xvB.z;
        }
    }
    #pragma unroll
    for (int k = 1; k < 16; k <<= 1){
        sA0 += __shfl_xor(sA0, k); sA1 += __shfl_xor(sA1, k);
        sA2 += __shfl_xor(sA2, k); spA += __shfl_xor(spA, k);
        sB0 += __shfl_xor(sB0, k); sB1 += __shfl_xor(sB1, k);
        sB2 += __shfl_xor(sB2, k); spB += __shfl_xor(spB, k);
    }
    int c = lane * 2;   // channels c,c+1 ; head (c>>5) == hsel
    float w0 = W1[c], w1 = W1[128+c], w2 = W1[256+c];
    float w0b = W1[c+1], w1b = W1[128+c+1], w2b = W1[256+c+1];
    float2 bb = *(const float2*)(b1 + c);
    float2 gg = *(const float2*)(g1 + c);
    float2 ee = *(const float2*)(be1 + c);
    // ---- epilogue node A ----
    {
        float inv = 1.f / (spA + 1e-16f);
        float A0 = sA0*inv, A1 = sA1*inv, A2 = sA2*inv;
        float h0 = A0*w0 + A1*w1 + A2*w2;
        float h1v= A0*w0b + A1*w1b + A2*w2b;
        float oA = eluf(h0 + bb.x);
        float oB = eluf(h1v + bb.y);
        float su = oA + oB;
        #pragma unroll
        for (int k = 32; k >= 1; k >>= 1) su += __shfl_xor(su, k);
        float mean = su * (1.f/128.f);
        float aA = oA - mean, aB = oB - mean;
        float vs = aA*aA + aB*aB;
        #pragma unroll
        for (int k = 32; k >= 1; k >>= 1) vs += __shfl_xor(vs, k);
        float rstd = rsqrtf(vs * (1.f/128.f) + LN_EPS);
        float rx = aA*rstd*gg.x + ee.x, ry = aB*rstd*gg.y + ee.y;
        h1b[(size_t)va*64 + lane] = (unsigned)f2bf(rx) | ((unsigned)f2bf(ry) << 16);
    }
    // ---- epilogue node B ----
    {
        float inv = 1.f / (spB + 1e-16f);
        float A0 = sB0*inv, A1 = sB1*inv, A2 = sB2*inv;
        float h0 = A0*w0 + A1*w1 + A2*w2;
        float h1v= A0*w0b + A1*w1b + A2*w2b;
        float oA = eluf(h0 + bb.x);
        float oB = eluf(h1v + bb.y);
        float su = oA + oB;
        #pragma unroll
        for (int k = 32; k >= 1; k >>= 1) su += __shfl_xor(su, k);
        float mean = su * (1.f/128.f);
        float aA = oA - mean, aB = oB - mean;
        float vs = aA*aA + aB*aB;
        #pragma unroll
        for (int k = 32; k >= 1; k >>= 1) vs += __shfl_xor(vs, k);
        float rstd = rsqrtf(vs * (1.f/128.f) + LN_EPS);
        float rx = aA*rstd*gg.x + ee.x, ry = aB*rstd*gg.y + ee.y;
        if (vbOK)
            h1b[(size_t)vb*64 + lane] = (unsigned)f2bf(rx) | ((unsigned)f2bf(ry) << 16);
    }
}

// ---------------- layer 2 linear via MFMA: h1b[N,128]bf16 @ W2[128,64] -> fp8 ----------------

__global__ __launch_bounds__(256) void k_lin2(
    const unsigned short* __restrict__ h1b,   // [N][128] bf16
    const float* __restrict__ W2,             // [128][64] fp32
    const float* __restrict__ asrc, const float* __restrict__ adst,
    unsigned char* __restrict__ h2b8, float* __restrict__ es2, float* __restrict__ ed2, int N)
{
    int t = threadIdx.x, lane = t & 63, w = t >> 6;
    int vb = blockIdx.x * 64 + w * 16;
    if (vb >= N) return;
    int lo4 = lane & 15, hi4 = lane >> 4;

    int arow = vb + lo4; if (arow >= N) arow = N - 1;
    const unsigned short* ap = h1b + (size_t)arow*128 + hi4*8;
    bf16x8 a0 = *(const bf16x8*)(ap);
    bf16x8 a1 = *(const bf16x8*)(ap + 32);
    bf16x8 a2 = *(const bf16x8*)(ap + 64);
    bf16x8 a3 = *(const bf16x8*)(ap + 96);

    f32x4 acc[4];
    #pragma unroll
    for (int nt = 0; nt < 4; ++nt) acc[nt] = (f32x4){0.f, 0.f, 0.f, 0.f};

    #pragma unroll
    for (int nt = 0; nt < 4; ++nt){
        int cb = nt*16 + lo4;
        #pragma unroll
        for (int kt = 0; kt < 4; ++kt){
            const float* wp = W2 + (size_t)(kt*32 + hi4*8)*64 + cb;
            bf16x8 b;
            #pragma unroll
            for (int j = 0; j < 8; ++j) b[j] = (short)f2bf(wp[(size_t)j*64]);
            bf16x8 a = (kt==0) ? a0 : (kt==1) ? a1 : (kt==2) ? a2 : a3;
            acc[nt] = __builtin_amdgcn_mfma_f32_16x16x32_bf16(a, b, acc[nt], 0, 0, 0);
        }
    }

    float sa0 = asrc[lo4], sa1 = asrc[16+lo4], sa2 = asrc[32+lo4], sa3 = asrc[48+lo4];
    float sb0 = adst[lo4], sb1 = adst[16+lo4], sb2 = adst[32+lo4], sb3 = adst[48+lo4];

    #pragma unroll
    for (int reg = 0; reg < 4; ++reg){
        int nr = vb + hi4*4 + reg;
        bool ok = nr < N;
        float c0 = acc[0][reg], c1 = acc[1][reg], c2 = acc[2][reg], c3 = acc[3][reg];
        if (ok){
            int wv = __builtin_amdgcn_cvt_pk_fp8_f32(c0, c1, 0, false);
            wv = __builtin_amdgcn_cvt_pk_fp8_f32(c2, c3, wv, true);
            unsigned char* hp = h2b8 + (size_t)nr*64 + lo4;
            hp[ 0] = (unsigned char)( wv        & 255);
            hp[16] = (unsigned char)((wv >>  8) & 255);
            hp[32] = (unsigned char)((wv >> 16) & 255);
            hp[48] = (unsigned char)((wv >> 24) & 255);
        }
        float ps0 = c0*sa0 + c1*sa1, ps1 = c2*sa2 + c3*sa3;
        float pd0 = c0*sb0 + c1*sb1, pd1 = c2*sb2 + c3*sb3;
        #pragma unroll
        for (int m = 8; m >= 1; m >>= 1){
            ps0 += __shfl_xor(ps0, m); ps1 += __shfl_xor(ps1, m);
            pd0 += __shfl_xor(pd0, m); pd1 += __shfl_xor(pd1, m);
        }
        if (ok && lo4 == 0){
            float2 e; e.x = ps0; e.y = ps1;
            float2 d; d.x = pd0; d.y = pd1;
            *(float2*)(es2 + (size_t)nr*2) = e;
            *(float2*)(ed2 + (size_t)nr*2) = d;
        }
    }
}

// ---------------- layer 2: fused attn+agg, fp8 rows, 2 nodes per wave ----------------
// lane = (slot g = lane>>4, l = lane&15); lane covers channels 4l..4l+3 (head l>>3).

__global__ __launch_bounds__(256) void k_agg2(
    const unsigned* __restrict__ h2b,          // [N][16] u32 = fp8[N][64]
    const float* __restrict__ es2, const float* __restrict__ ed2,
    const int* __restrict__ row_ptr, const int* __restrict__ col,
    const float4* __restrict__ x4, const float* __restrict__ Wskip, const float* __restrict__ bskip,
    const float* __restrict__ b2, const float* __restrict__ g2, const float* __restrict__ be2,
    float* __restrict__ h2, int N)
{
    __shared__ float sp[4][2][2][68];   // [wave][node][head][edge]
    int t = threadIdx.x, lane = t & 63, w = t >> 6;
    int va = blockIdx.x * 8 + w * 2;
    if (va >= N) return;
    int vb = va + 1;
    bool vbOK = vb < N;
    int vbL = vbOK ? vb : va;
    int g = lane >> 4, l = lane & 15;
    int hsel = l >> 3;
    float2 edvA = *(const float2*)(ed2 + (size_t)va*2);
    float2 esvA = *(const float2*)(es2 + (size_t)va*2);
    float2 edvB = *(const float2*)(ed2 + (size_t)vbL*2);
    float2 esvB = *(const float2*)(es2 + (size_t)vbL*2);
    float ehA = (hsel ? esvA.y : esvA.x) + (hsel ? edvA.y : edvA.x);
    float ehB = (hsel ? esvB.y : esvB.x) + (hsel ? edvB.y : edvB.x);
    float pselfA = (g == 0) ? __expf(lrelu(ehA)) : 0.f;
    float pselfB = (g == 0 && vbOK) ? __expf(lrelu(ehB)) : 0.f;
    unsigned usA = h2b[(size_t)va*16 + l];
    unsigned usB = h2b[(size_t)vbL*16 + l];
    f32x2 aA01, aA23, aB01, aB23;
    {
        f32x2 psA = {pselfA, pselfA}, psB = {pselfB, pselfB};
        aA01 = psA * __builtin_amdgcn_cvt_pk_f32_fp8((int)usA, false);
        aA23 = psA * __builtin_amdgcn_cvt_pk_f32_fp8((int)usA, true);
        aB01 = psB * __builtin_amdgcn_cvt_pk_f32_fp8((int)usB, false);
        aB23 = psB * __builtin_amdgcn_cvt_pk_f32_fp8((int)usB, true);
    }
    float sum_pA = pselfA, sum_pB = pselfB;

    int baseA = row_ptr[va], endA = row_ptr[va+1];
    int baseB = 0, endB = 0;
    if (vbOK){ baseB = row_ptr[vb]; endB = row_ptr[vb+1]; }
    while (baseA < endA || baseB < endB){
        int cA = endA - baseA; cA = cA < 0 ? 0 : (cA > 64 ? 64 : cA);
        int cB = endB - baseB; cB = cB < 0 ? 0 : (cB > 64 ? 64 : cB);
        int sregA = 0, sregB = 0;
        if (lane < cA){
            sregA = col[baseA + lane];
            float2 q = *(const float2*)(es2 + (size_t)sregA*2);
            sp[w][0][0][lane] = __expf(lrelu(q.x + edvA.x));
            sp[w][0][1][lane] = __expf(lrelu(q.y + edvA.y));
        }
        if (lane < cB){
            sregB = col[baseB + lane];
            float2 q = *(const float2*)(es2 + (size_t)sregB*2);
            sp[w][1][0][lane] = __expf(lrelu(q.x + edvB.x));
            sp[w][1][1][lane] = __expf(lrelu(q.y + edvB.y));
        }
        asm volatile("s_waitcnt lgkmcnt(0)" ::: "memory");
        int cmax = cA > cB ? cA : cB;
        for (int i = 0; i < cmax; i += 16){
            int e0 = i + g, e1 = e0 + 4, e2 = e0 + 8, e3 = e0 + 12;
            // node A
            int sa0 = __shfl(sregA, e0), sa1 = __shfl(sregA, e1);
            int sa2 = __shfl(sregA, e2), sa3 = __shfl(sregA, e3);
            bool a0 = e0 < cA, a1 = e1 < cA, a2 = e2 < cA, a3 = e3 < cA;
            if (!a0) sa0 = va;  if (!a1) sa1 = va;  if (!a2) sa2 = va;  if (!a3) sa3 = va;
            // node B
            int sb0 = __shfl(sregB, e0), sb1 = __shfl(sregB, e1);
            int sb2 = __shfl(sregB, e2), sb3 = __shfl(sregB, e3);
            bool b0 = e0 < cB, b1 = e1 < cB, b2 = e2 < cB, b3 = e3 < cB;
            if (!b0) sb0 = va;  if (!b1) sb1 = va;  if (!b2) sb2 = va;  if (!b3) sb3 = va;
            // issue all 8 independent gathers
            unsigned uA0 = h2b[(size_t)sa0*16 + l];
            unsigned uA1 = h2b[(size_t)sa1*16 + l];
            unsigned uA2 = h2b[(size_t)sa2*16 + l];
            unsigned uA3 = h2b[(size_t)sa3*16 + l];
            unsigned uB0 = h2b[(size_t)sb0*16 + l];
            unsigned uB1 = h2b[(size_t)sb1*16 + l];
            unsigned uB2 = h2b[(size_t)sb2*16 + l];
            unsigned uB3 = h2b[(size_t)sb3*16 + l];
            float pA0 = a0 ? sp[w][0][hsel][e0] : 0.f;
            float pA1 = a1 ? sp[w][0][hsel][e1] : 0.f;
            float pA2 = a2 ? sp[w][0][hsel][e2] : 0.f;
            float pA3 = a3 ? sp[w][0][hsel][e3] : 0.f;
            float pB0 = b0 ? sp[w][1][hsel][e0] : 0.f;
            float pB1 = b1 ? sp[w][1][hsel][e1] : 0.f;
            float pB2 = b2 ? sp[w][1][hsel][e2] : 0.f;
            float pB3 = b3 ? sp[w][1][hsel][e3] : 0.f;
            sum_pA += (pA0 + pA1) + (pA2 + pA3);
            sum_pB += (pB0 + pB1) + (pB2 + pB3);
            f32x2 vA0 = {pA0,pA0}, vA1 = {pA1,pA1}, vA2 = {pA2,pA2}, vA3 = {pA3,pA3};
            f32x2 vB0 = {pB0,pB0}, vB1 = {pB1,pB1}, vB2 = {pB2,pB2}, vB3 = {pB3,pB3};
            aA01 += vA0 * __builtin_amdgcn_cvt_pk_f32_fp8((int)uA0, false)
                  + vA1 * __builtin_amdgcn_cvt_pk_f32_fp8((int)uA1, false)
                  + vA2 * __builtin_amdgcn_cvt_pk_f32_fp8((int)uA2, false)
                  + vA3 * __builtin_amdgcn_cvt_pk_f32_fp8((int)uA3, false);
            aA23 += vA0 * __builtin_amdgcn_cvt_pk_f32_fp8((int)uA0, true)
                  + vA1 * __builtin_amdgcn_cvt_pk_f32_fp8((int)uA1, true)
                  + vA2 * __builtin_amdgcn_cvt_pk_f32_fp8((int)uA2, true)
                  + vA3 * __builtin_amdgcn_cvt_pk_f32_fp8((int)uA3, true);
            aB01 += vB0 * __builtin_amdgcn_cvt_pk_f32_fp8((int)uB0, false)
                  + vB1 * __builtin_amdgcn_cvt_pk_f32_fp8((int)uB1, false)
                  + vB2 * __builtin_amdgcn_cvt_pk_f32_fp8((int)uB2, false)
                  + vB3 * __builtin_amdgcn_cvt_pk_f32_fp8((int)uB3, false);
            aB23 += vB0 * __builtin_amdgcn_cvt_pk_f32_fp8((int)uB0, true)
                  + vB1 * __builtin_amdgcn_cvt_pk_f32_fp8((int)uB1, true)
                  + vB2 * __builtin_amdgcn_cvt_pk_f32_fp8((int)uB2, true)
                  + vB3 * __builtin_amdgcn_cvt_pk_f32_fp8((int)uB3, true);
        }
        baseA += 64; baseB += 64;
    }
    int cc = (l & 7) * 4;
    float4 bv = *(const float4*)(b2 + cc);
    float4 gv = *(const float4*)(g2 + cc);
    float4 ev = *(const float4*)(be2 + cc);
    float wk0[4], wk1[4], wk2[4], bkv[4];
    #pragma unroll
    for (int j = 0; j < 4; ++j){
        wk0[j] = Wskip[cc+j]; wk1[j] = Wskip[32+cc+j]; wk2[j] = Wskip[64+cc+j];
        bkv[j] = bskip[cc+j];
    }
    // ---- epilogue node A ----
    {
        float acc[4] = {aA01.x, aA01.y, aA23.x, aA23.y};
        #pragma unroll
        for (int j = 0; j < 4; ++j){
            acc[j] += __shfl_xor(acc[j], 16);
            acc[j] += __shfl_xor(acc[j], 32);
        }
        float sp_ = sum_pA;
        sp_ += __shfl_xor(sp_, 16); sp_ += __shfl_xor(sp_, 32);
        float inv = 1.f / (sp_ + 1e-16f);
        #pragma unroll
        for (int j = 0; j < 4; ++j) acc[j] *= inv;
        float4 xv = x4[va];
        float z[4];
        float bvv[4] = {bv.x, bv.y, bv.z, bv.w};
        #pragma unroll
        for (int j = 0; j < 4; ++j){
            float other = __shfl_xor(acc[j], 8);
            float o = eluf(0.5f*(acc[j] + other) + bvv[j]);
            float sk = xv.x*wk0[j] + xv.y*wk1[j] + xv.z*wk2[j] + bkv[j];
            z[j] = o + sk;
        }
        float su = z[0]+z[1]+z[2]+z[3];
        su += __shfl_xor(su,1); su += __shfl_xor(su,2); su += __shfl_xor(su,4);
        float mean = su * (1.f/32.f);
        float vs = 0.f;
        #pragma unroll
        for (int j = 0; j < 4; ++j){ float d = z[j]-mean; vs += d*d; }
        vs += __shfl_xor(vs,1); vs += __shfl_xor(vs,2); vs += __shfl_xor(vs,4);
        float rstd = rsqrtf(vs * (1.f/32.f) + LN_EPS);
        if (g == 0 && l < 8){
            float4 r;
            r.x = (z[0]-mean)*rstd*gv.x + ev.x;
            r.y = (z[1]-mean)*rstd*gv.y + ev.y;
            r.z = (z[2]-mean)*rstd*gv.z + ev.z;
            r.w = (z[3]-mean)*rstd*gv.w + ev.w;
            *(float4*)(h2 + (size_t)va*32 + cc) = r;
        }
    }
    // ---- epilogue node B ----
    {
        float acc[4] = {aB01.x, aB01.y, aB23.x, aB23.y};
        #pragma unroll
        for (int j = 0; j < 4; ++j){
            acc[j] += __shfl_xor(acc[j], 16);
            acc[j] += __shfl_xor(acc[j], 32);
        }
        float sp_ = sum_pB;
        sp_ += __shfl_xor(sp_, 16); sp_ += __shfl_xor(sp_, 32);
        float inv = 1.f / (sp_ + 1e-16f);
        #pragma unroll
        for (int j = 0; j < 4; ++j) acc[j] *= inv;
        float4 xv = x4[vbL];
        float z[4];
        float bvv[4] = {bv.x, bv.y, bv.z, bv.w};
        #pragma unroll
        for (int j = 0; j < 4; ++j){
            float other = __shfl_xor(acc[j], 8);
            float o = eluf(0.5f*(acc[j] + other) + bvv[j]);
            float sk = xv.x*wk0[j] + xv.y*wk1[j] + xv.z*wk2[j] + bkv[j];
            z[j] = o + sk;
        }
        float su = z[0]+z[1]+z[2]+z[3];
        su += __shfl_xor(su,1); su += __shfl_xor(su,2); su += __shfl_xor(su,4);
        float mean = su * (1.f/32.f);
        float vs = 0.f;
        #pragma unroll
        for (int j = 0; j < 4; ++j){ float d = z[j]-mean; vs += d*d; }
        vs += __shfl_xor(vs,1); vs += __shfl_xor(vs,2); vs += __shfl_xor(vs,4);
        float rstd = rsqrtf(vs * (1.f/32.f) + LN_EPS);
        if (vbOK && g == 0 && l < 8){
            float4 r;
            r.x = (z[0]-mean)*rstd*gv.x + ev.x;
            r.y = (z[1]-mean)*rstd*gv.y + ev.y;
            r.z = (z[2]-mean)*rstd*gv.z + ev.z;
            r.w = (z[3]-mean)*rstd*gv.w + ev.w;
            *(float4*)(h2 + (size_t)vb*32 + cc) = r;
        }
    }
}

// ---------------- pooling: per-graph mean/max/std (batch sorted) + projection ----------------

__global__ __launch_bounds__(256) void k_pool(
    const float* __restrict__ h2, const int* __restrict__ batch,
    const float* __restrict__ Wp, const float* __restrict__ bp,
    float* __restrict__ out, int N)
{
    int g = blockIdx.x; int t = threadIdx.x;
    __shared__ int sBeg, sEnd;
    if (t == 0){
        int lo = 0, hi = N;
        while (lo < hi){ int mid = (lo+hi) >> 1; if (batch[mid] < g) lo = mid+1; else hi = mid; }
        sBeg = lo;
        lo = sBeg; hi = N;
        while (lo < hi){ int mid = (lo+hi) >> 1; if (batch[mid] < g+1) lo = mid+1; else hi = mid; }
        sEnd = lo;
    }
    __syncthreads();
    int beg = sBeg, end = sEnd;
    int ch = t & 31, grp = t >> 5;
    float sum = 0.f, sq = 0.f, mx = -INFINITY;
    for (int i = beg + grp; i < end; i += 8){
        float val = h2[(size_t)i*32 + ch];
        sum += val; sq += val*val; mx = fmaxf(mx, val);
    }
    __shared__ float lsum[256], lsq[256], lmx[256];
    lsum[t] = sum; lsq[t] = sq; lmx[t] = mx;
    __syncthreads();
    for (int s = 4; s >= 1; s >>= 1){
        if (grp < s){
            lsum[t] += lsum[t + s*32];
            lsq [t] += lsq [t + s*32];
            lmx [t]  = fmaxf(lmx[t], lmx[t + s*32]);
        }
        __syncthreads();
    }
    __shared__ float feat[96];
    if (t < 32){
        float cnt = fmaxf((float)(end - beg), 1.f);
        float mean = lsum[t] / cnt;
        float var  = lsq[t] / cnt - mean*mean;
        feat[t]      = mean;
        feat[32 + t] = lmx[t];
        feat[64 + t] = sqrtf(fmaxf(var, 0.f));
    }
    __syncthreads();
    if (t < 48){
        float acc = bp[t];
        #pragma unroll 8
        for (int k = 0; k < 96; ++k) acc += feat[k] * Wp[k*48 + t];
        out[(size_t)g*48 + t] = acc;
    }
}

// ---------------- launcher ----------------

extern "C" void kernel_launch(void* const* d_in, const int* in_sizes, int n_in,
                              void* d_out, int out_size, void* d_ws, size_t ws_size,
                              hipStream_t stream)
{
    const float* x     = (const float*)d_in[0];
    const int*   ei    = (const int*)  d_in[1];
    const int*   batch = (const int*)  d_in[2];
    const float* W1    = (const float*)d_in[3];
    const float* as1   = (const float*)d_in[4];
    const float* ad1   = (const float*)d_in[5];
    const float* b1    = (const float*)d_in[6];
    const float* W2    = (const float*)d_in[7];
    const float* as2   = (const float*)d_in[8];
    const float* ad2   = (const float*)d_in[9];
    const float* b2    = (const float*)d_in[10];
    const float* Wskip = (const float*)d_in[11];
    const float* bskip = (const float*)d_in[12];
    const float* g1    = (const float*)d_in[13];
    const float* be1   = (const float*)d_in[14];
    const float* g2    = (const float*)d_in[15];
    const float* be2   = (const float*)d_in[16];
    const float* Wp    = (const float*)d_in[17];
    const float* bp    = (const float*)d_in[18];

    int N = in_sizes[0] / 3;
    int E = in_sizes[1] / 2;
    int B = out_size / 48;
    const int* src = ei;
    const int* dst = ei + E;
    int NBUK = (N + 63) / 64;              // 1563
    int chunk = (E + NWG - 1) / NWG;
    int M = NBUK * NWG;                    // 400128

    char* w = (char*)d_ws;
    auto alloc = [&](size_t bytes) -> char* {
        char* p = w; w += (bytes + 255) & ~(size_t)255; return p;
    };
    int*   row_ptr = (int*)  alloc((size_t)(N+1)*4);
    int*   hist    = (int*)  alloc((size_t)M*4);
    int*   p1      = (int*)  alloc(8*1024);            // level-1 partials (<=2048)
    int*   col     = (int*)  alloc((size_t)E*4);
    unsigned* h2b  = (unsigned*)alloc((size_t)N*64);   // fp8[N][64]
    float* es      = (float*)alloc((size_t)N*2*4);     // layer2 es2
    float* ed      = (float*)alloc((size_t)N*2*4);     // layer2 ed2
    unsigned* h1b  = (unsigned*)alloc((size_t)N*64*4); // bf16[N][128]
    float* h2      = (float*)alloc((size_t)N*32*4);
    float4* x4     = (float4*)alloc((size_t)N*16);
    unsigned* ebuf = (unsigned*)h2;                    // alias: ebuf dead before agg2 writes h2
    (void)ws_size;

    int mb  = (M + 255) / 256;             // 1563 <= 2048: single-block mid scan ok
    int nb8 = (N + 7) / 8;
    int nb2 = (N + 63) / 64;

    k_hist        <<<NWG, 512, 0, stream>>>(dst, hist, x, x4, E, NBUK, chunk, N);
    k_chunk_sum   <<<mb, 256, 0, stream>>>(hist, p1, M);
    k_scan_mid    <<<1, 1024, 0, stream>>>(p1, mb);
    k_scan_apply  <<<mb, 256, 0, stream>>>(hist, p1, M);
    k_pscatter    <<<NWG, 512, 0, stream>>>(src, dst, hist, ebuf, E, NBUK, chunk);
    k_bfill       <<<(NBUK + 3) / 4, 256, 0, stream>>>(ebuf, hist, row_ptr, col, N, NBUK, E);

    k_agg1 <<<nb8, 256, 0, stream>>>(x4, W1, as1, ad1, row_ptr, col, b1, g1, be1, h1b, N);
    k_lin2 <<<nb2, 256, 0, stream>>>((const unsigned short*)h1b, W2, as2, ad2,
                                     (unsigned char*)h2b, es, ed, N);
    k_agg2 <<<nb8, 256, 0, stream>>>(h2b, es, ed, row_ptr, col,
                                     x4, Wskip, bskip, b2, g2, be2, h2, N);
    k_pool <<<B, 256, 0, stream>>>(h2, batch, Wp, bp, (float*)d_out, N);
}